// Round 19
// baseline (500.175 us; speedup 1.0000x reference)
//
#include <hip/hip_runtime.h>

#define S_LEN 2048
#define HID 4096
#define NH 32
#define HD 128
#define QKV_N 12288   // 3*HID

typedef __attribute__((ext_vector_type(8))) short bf16x8;
typedef __attribute__((ext_vector_type(4))) float f32x4;

__device__ __forceinline__ unsigned short f2bf(float f) {
    unsigned int u = __float_as_uint(f);
    u += 0x7FFF + ((u >> 16) & 1);
    return (unsigned short)(u >> 16);
}
__device__ __forceinline__ float bf2f(unsigned short h) {
    return __uint_as_float(((unsigned int)h) << 16);
}

typedef __attribute__((address_space(1))) const void gconst_void;
typedef __attribute__((address_space(3))) void lds_void;
__device__ __forceinline__ void gl16(const void* g, void* l) {
    __builtin_amdgcn_global_load_lds((gconst_void*)g, (lds_void*)l, 16, 0, 0);
}

#define VMCNT(n) asm volatile("s_waitcnt vmcnt(" #n ")" ::: "memory")
#define BAR()    do { asm volatile("" ::: "memory"); __builtin_amdgcn_s_barrier(); asm volatile("" ::: "memory"); } while (0)

// ---------------- fp32 -> bf16 linear convert ----------------
__global__ __launch_bounds__(256)
void cvt_f32_bf16(const float* __restrict__ in, unsigned short* __restrict__ out, int n8)
{
    int i = blockIdx.x * 256 + threadIdx.x;
    if (i >= n8) return;
    const float4* p = (const float4*)in + (size_t)i * 2;
    float4 a = p[0], b = p[1];
    bf16x8 o;
    o[0] = (short)f2bf(a.x); o[1] = (short)f2bf(a.y); o[2] = (short)f2bf(a.z); o[3] = (short)f2bf(a.w);
    o[4] = (short)f2bf(b.x); o[5] = (short)f2bf(b.y); o[6] = (short)f2bf(b.z); o[7] = (short)f2bf(b.w);
    *((bf16x8*)out + i) = o;
}

// ---------------- fp32 [K][N] -> bf16 [N][K] transpose-convert (up to 3 weights) ----------------
struct W3 { const float* w0; const float* w1; const float* w2; };

__global__ __launch_bounds__(256)
void cvt_w_t3(W3 ws3, unsigned short* __restrict__ Wt, int N, int K)
{
    __shared__ unsigned short t[64][72];
    const float* W = blockIdx.z == 0 ? ws3.w0 : (blockIdx.z == 1 ? ws3.w1 : ws3.w2);
    unsigned short* Wto = Wt + (size_t)blockIdx.z * N * K;
    const int tid = threadIdx.x;
    const int n0 = blockIdx.x * 64, k0 = blockIdx.y * 64;
    const int c4 = (tid & 15) * 4;
    const int r  = tid >> 4;
    #pragma unroll
    for (int p = 0; p < 4; ++p) {
        float4 v = *(const float4*)&W[(size_t)(k0 + r + p * 16) * N + n0 + c4];
        ushort4 o;
        o.x = f2bf(v.x); o.y = f2bf(v.y); o.z = f2bf(v.z); o.w = f2bf(v.w);
        *(ushort4*)&t[r + p * 16][c4] = o;
    }
    __syncthreads();
    const int n = tid >> 2;
    const int kq = (tid & 3) * 16;
    unsigned short* dst = &Wto[(size_t)(n0 + n) * K + k0 + kq];
    bf16x8 v0, v1;
    #pragma unroll
    for (int j = 0; j < 8; ++j) v0[j] = (short)t[kq + j][n];
    #pragma unroll
    for (int j = 0; j < 8; ++j) v1[j] = (short)t[kq + 8 + j][n];
    *(bf16x8*)dst = v0;
    *(bf16x8*)(dst + 8) = v1;
}

// ---------------- bf16 V slab [s][c] -> Vtg [c][s] transpose (+ optional split-K combine) ----------------
template<bool SPLIT>
__global__ __launch_bounds__(256)
void v_transpose(const unsigned short* __restrict__ P0, const unsigned short* __restrict__ P1,
                 unsigned short* __restrict__ Vtg)
{
    __shared__ unsigned short t[64][72];
    const int tid = threadIdx.x;
    const int s0 = blockIdx.x * 64;
    const int c0 = blockIdx.y * 64;
    #pragma unroll
    for (int i = 0; i < 2; ++i) {
        int idx = i * 256 + tid;
        int r = idx >> 3, c8 = (idx & 7) * 8;
        size_t off = (size_t)(s0 + r) * QKV_N + 2 * HID + c0 + c8;
        bf16x8 a = *(const bf16x8*)&P0[off];
        if (SPLIT) {
            bf16x8 b = *(const bf16x8*)&P1[off];
            #pragma unroll
            for (int j = 0; j < 8; ++j)
                a[j] = (short)f2bf(bf2f((unsigned short)a[j]) + bf2f((unsigned short)b[j]));
        }
        *(bf16x8*)&t[r][c8] = a;
    }
    __syncthreads();
    #pragma unroll
    for (int i = 0; i < 2; ++i) {
        int idx = i * 256 + tid;
        int oc = idx >> 3, os8 = (idx & 7) * 8;
        bf16x8 v;
        #pragma unroll
        for (int j = 0; j < 8; ++j) v[j] = (short)t[os8 + j][oc];
        *(bf16x8*)&Vtg[(size_t)(c0 + oc) * S_LEN + s0 + os8] = v;
    }
}

// ---------------- QKV GEMM: 256x256 tile, BK=32, 1024 threads, 64KB LDS -> 2 blocks/CU ----------------
// r19: cross-block occupancy overlap (m114 mechanism); free-run single barrier per K-tile
__global__ __launch_bounds__(1024)
void gemm_qkv(const unsigned short* __restrict__ A,   // [M][ldk] bf16
              const unsigned short* __restrict__ Bt,  // [N][ldk] bf16
              unsigned short* __restrict__ Cp,        // bf16, + z*zstride
              int N, int K, int ldk, size_t zstride)
{
    extern __shared__ char lds[];   // buf at (t&1)*32768: A[256][64B] @0 | B[256][64B] @16384
    const int tid = threadIdx.x;
    const int l   = tid & 63;
    const int l15 = l & 15, lg = l >> 4;
    const int wid = tid >> 6;       // 0..15
    const int wr  = wid >> 2;       // 0..3
    const int wc  = wid & 3;        // 0..3

    // column-slab XCD mapping (r6-verified)
    const int nwg = gridDim.x;
    const int bid = blockIdx.x;
    const int ntx = N >> 8;
    const int nty = nwg / ntx;
    const int cpx = ntx >> 3;
    const int xcd = bid & 7;
    const int idx = bid >> 3;
    const int bx = xcd * cpx + idx / nty;
    const int by = idx % nty;
    const int m0 = by * 256, n0 = bx * 256;
    const int koff = blockIdx.z * K;

    // staging: 1 gl16/thread per operand; pre-swizzled global chunk sg = sc ^ (sr&3)
    const int sr = tid >> 2;        // 0..255 (tile row)
    const int sc = tid & 3;         // 16B chunk in 64B row
    const int sg = sc ^ (sr & 3);
    const unsigned short* Ag = A  + (size_t)(m0 + sr) * ldk + koff + sg * 8;
    const unsigned short* Bg = Bt + (size_t)(n0 + sr) * ldk + koff + sg * 8;
    const int dstA = tid * 16;           // = sr*64 + sc*16 (linear per wave)
    const int dstB = 16384 + tid * 16;

    f32x4 acc[4][4] = {};
    bf16x8 af[4], bf[4];

    gl16(Ag, lds + dstA);
    gl16(Bg, lds + dstB);
    VMCNT(0);
    BAR();

    const int NT = K >> 5;
    for (int t = 0; t < NT; ++t) {
        const int cb = (t & 1) * 32768, nb = cb ^ 32768;
        const int kn = (t + 1) << 5;
        const bool hn = (t + 1) < NT;

        #pragma unroll
        for (int mi = 0; mi < 4; ++mi) {
            int row = wr * 64 + mi * 16 + l15;
            af[mi] = *(const bf16x8*)(lds + cb + row * 64 + ((lg ^ (row & 3)) << 4));
        }
        #pragma unroll
        for (int nj = 0; nj < 4; ++nj) {
            int row = wc * 64 + nj * 16 + l15;
            bf[nj] = *(const bf16x8*)(lds + cb + 16384 + row * 64 + ((lg ^ (row & 3)) << 4));
        }
        if (hn) {
            gl16(Ag + kn, lds + nb + dstA);
            gl16(Bg + kn, lds + nb + dstB);
        }
        __builtin_amdgcn_s_setprio(1);
        #pragma unroll
        for (int mi = 0; mi < 4; ++mi)
            #pragma unroll
            for (int nj = 0; nj < 4; ++nj)
                acc[mi][nj] = __builtin_amdgcn_mfma_f32_16x16x32_bf16(af[mi], bf[nj], acc[mi][nj], 0, 0, 0);
        __builtin_amdgcn_s_setprio(0);
        VMCNT(0);   // own 2 stages; other resident block hides the wait
        BAR();
    }

    unsigned short* C = Cp + (size_t)blockIdx.z * zstride;
    const int crow = m0 + wr * 64 + lg * 4;
    const int ccol = n0 + wc * 64 + l15;
    #pragma unroll
    for (int mi = 0; mi < 4; ++mi)
        #pragma unroll
        for (int nj = 0; nj < 4; ++nj)
            #pragma unroll
            for (int rr = 0; rr < 4; ++rr)
                C[(size_t)(crow + mi * 16 + rr) * N + ccol + nj * 16] = f2bf(acc[mi][nj][rr]);
}

// ---------------- 128x256 GEMM -> fp32 out (Wo projection; 256 blocks, r18-verified) ----------------
__global__ __launch_bounds__(512, 2)
void gemm_wo(const unsigned short* __restrict__ A,   // [M][K] bf16 (M=2048)
             const unsigned short* __restrict__ Bt,  // [N][K] bf16 (N=4096)
             float* __restrict__ out, int N, int K)
{
    extern __shared__ char lds[];
    const int tid = threadIdx.x;
    const int l   = tid & 63;
    const int l15 = l & 15, lg = l >> 4;
    const int wid = tid >> 6;
    const int wr  = wid >> 2;
    const int wc  = wid & 3;

    const int bid = blockIdx.x;
    const int ntx = N >> 8;
    const int nty = 256 / ntx;
    const int cpx = ntx >> 3;
    const int xcd = bid & 7;
    const int idx = bid >> 3;
    const int bx = xcd * cpx + idx / nty;
    const int by = idx % nty;
    const int m0 = by * 128, n0 = bx * 256;

    const int r8 = tid >> 3;
    const int swslot = ((tid & 7) ^ (r8 & 7)) << 3;

    const unsigned short* Ag = A  + (size_t)(m0 + r8) * K + swslot;
    const unsigned short* Bg = Bt + (size_t)(n0 + r8) * K + swslot;

    f32x4 acc[4][4] = {};
    bf16x8 af[4][2], bf[4][2];

    #pragma unroll
    for (int i = 0; i < 2; ++i)
        gl16(Ag + (size_t)i * 64 * K, lds + (i * 512 + tid) * 16);
    #pragma unroll
    for (int i = 0; i < 4; ++i)
        gl16(Bg + (size_t)i * 64 * K, lds + 16384 + (i * 512 + tid) * 16);
    VMCNT(0);
    BAR();

    const int NT = K >> 6;
    for (int t = 0; t < NT; ++t) {
        const int cb = (t & 1) * 49152, nb = cb ^ 49152;
        const int kn = (t + 1) << 6;
        const bool hn = (t + 1) < NT;

        const int sw = (l15 & 7) << 4;
        #pragma unroll
        for (int mi = 0; mi < 4; ++mi) {
            const char* rb = lds + cb + (wr * 64 + mi * 16 + l15) * 128;
            af[mi][0] = *(const bf16x8*)(rb + ((lg * 16) ^ sw));
            af[mi][1] = *(const bf16x8*)(rb + ((64 + lg * 16) ^ sw));
        }
        #pragma unroll
        for (int nj = 0; nj < 4; ++nj) {
            const char* rb = lds + cb + 16384 + (wc * 64 + nj * 16 + l15) * 128;
            bf[nj][0] = *(const bf16x8*)(rb + ((lg * 16) ^ sw));
            bf[nj][1] = *(const bf16x8*)(rb + ((64 + lg * 16) ^ sw));
        }
        if (hn) {
            #pragma unroll
            for (int i = 0; i < 2; ++i)
                gl16(Ag + (size_t)i * 64 * K + kn, lds + nb + (i * 512 + tid) * 16);
            #pragma unroll
            for (int i = 0; i < 4; ++i)
                gl16(Bg + (size_t)i * 64 * K + kn, lds + nb + 16384 + (i * 512 + tid) * 16);
        }
        __builtin_amdgcn_s_setprio(1);
        #pragma unroll
        for (int kk = 0; kk < 2; ++kk)
            #pragma unroll
            for (int mi = 0; mi < 4; ++mi)
                #pragma unroll
                for (int nj = 0; nj < 4; ++nj)
                    acc[mi][nj] = __builtin_amdgcn_mfma_f32_16x16x32_bf16(af[mi][kk], bf[nj][kk], acc[mi][nj], 0, 0, 0);
        __builtin_amdgcn_s_setprio(0);

        VMCNT(0);
        BAR();
    }

    const int crow = m0 + wr * 64 + lg * 4;
    const int ccol = n0 + wc * 64 + l15;
    #pragma unroll
    for (int mi = 0; mi < 4; ++mi)
        #pragma unroll
        for (int nj = 0; nj < 4; ++nj)
            #pragma unroll
            for (int rr = 0; rr < 4; ++rr)
                out[(size_t)(crow + mi * 16 + rr) * N + ccol + nj * 16] = acc[mi][nj][rr];
}

// ---------------- per-head LayerNorm + RoPE (+ optional split-K combine), writes into P0 ----------------
template<bool SPLIT>
__global__ __launch_bounds__(256)
void ln_rope(unsigned short* __restrict__ P0, const unsigned short* __restrict__ P1,
             const float* __restrict__ qg, const float* __restrict__ qb,
             const float* __restrict__ kg, const float* __restrict__ kb,
             const int* __restrict__ pos)
{
    const int tid = threadIdx.x;
    const int l = tid & 63;
    const int w = tid >> 6;
    const int rid = blockIdx.x * 4 + w;
    const int s = rid >> 6;
    const int hh = rid & 63;
    const int which = hh >> 5;
    const int h = hh & 31;
    const size_t off = (size_t)s * QKV_N + which * HID + h * HD;
    unsigned short* p = P0 + off;
    const float* gamma = which ? kg : qg;
    const float* beta  = which ? kb : qb;

    float lo = bf2f(p[l]);
    float hi = bf2f(p[l + 64]);
    if (SPLIT) {
        const unsigned short* q = P1 + off;
        lo += bf2f(q[l]);
        hi += bf2f(q[l + 64]);
    }
    float sum = lo + hi;
    #pragma unroll
    for (int off2 = 32; off2 >= 1; off2 >>= 1) sum += __shfl_xor(sum, off2, 64);
    float mu = sum * (1.0f / 128.0f);
    float dlo = lo - mu, dhi = hi - mu;
    float vs = dlo * dlo + dhi * dhi;
    #pragma unroll
    for (int off2 = 32; off2 >= 1; off2 >>= 1) vs += __shfl_xor(vs, off2, 64);
    float rstd = rsqrtf(vs * (1.0f / 128.0f) + 1e-5f);
    float xlo = dlo * rstd * gamma[l] + beta[l];
    float xhi = dhi * rstd * gamma[l + 64] + beta[l + 64];

    float fpos = (float)pos[s];
    float invf = exp2f(-13.287712379549449f * (float)l * (1.0f / 64.0f));
    float ang = fpos * invf;
    float sn, cs;
    sincosf(ang, &sn, &cs);
    p[l]      = f2bf(xlo * cs - xhi * sn);
    p[l + 64] = f2bf(xhi * cs + xlo * sn);
}

// ---------------- causal flash attention: 8 waves (QBLK=128), KVB=128, 1 barrier/tile ----------------
#define KVB 128
#define ATTN_LDS 149504

__global__ __launch_bounds__(512)
void attn_fwd(const unsigned short* __restrict__ QKV,   // [S][12288]
              const unsigned short* __restrict__ Vtg,   // [4096][S]
              unsigned short* __restrict__ O)           // [S][4096]
{
    extern __shared__ char shb[];
    unsigned short* const Psw = (unsigned short*)(shb + 131072) + (threadIdx.x >> 6) * (16 * 72);

    const int tid = threadIdx.x;
    const int l = tid & 63;
    const int w = tid >> 6;
    const int l15 = l & 15, lg = l >> 4;
    const int h = blockIdx.y;
    const int qb = gridDim.x - 1 - blockIdx.x;
    const int q0 = qb * 128;
    const int qw = q0 + w * 16;

    const unsigned short* Qp = QKV + h * HD;
    const unsigned short* Kp = QKV + HID + h * HD;
    const unsigned short* Vp = Vtg + (size_t)h * HD * S_LEN;

    bf16x8 qf[4];
    #pragma unroll
    for (int d = 0; d < 4; ++d)
        qf[d] = *(const bf16x8*)&Qp[(size_t)(qw + l15) * QKV_N + d * 32 + lg * 8];

    f32x4 o_acc[8] = {};
    float mgrp = -1e30f;
    float lsum[4] = {0.0f, 0.0f, 0.0f, 0.0f};

    const float scale = 0.08838834764831845f;

    const int ksl = tid & 15;
    const int kr7 = (tid >> 4) & 7;
    const int ksg = (ksl & 8) | ((ksl ^ kr7) & 7);
    const unsigned short* Kg = Kp + (size_t)(tid >> 4) * QKV_N + ksg * 8;
    const unsigned short* Vg = Vp + (size_t)(tid >> 4) * S_LEN + ksg * 8;

#define STAGE(buf, kv0s) do {                                                          \
    _Pragma("unroll")                                                                  \
    for (int i_ = 0; i_ < 4; ++i_)                                                     \
        gl16(Kg + (size_t)((kv0s) + i_ * 32) * QKV_N,                                  \
             shb + (buf) * 32768 + (i_ * 512 + tid) * 16);                             \
    _Pragma("unroll")                                                                  \
    for (int i_ = 0; i_ < 4; ++i_)                                                     \
        gl16(Vg + (size_t)i_ * 32 * S_LEN + (kv0s),                                    \
             shb + 65536 + (buf) * 32768 + (i_ * 512 + tid) * 16);                     \
} while (0)

    STAGE(0, 0);
    VMCNT(0);
    __syncthreads();

    const int nt = qb + 1;
    for (int t = 0; t < nt; ++t) {
        const int kv0 = t * KVB;
        const int cur = t & 1;
        const bool hn = (t + 1) < nt;
        if (hn) STAGE(cur ^ 1, kv0 + KVB);

        f32x4 sc[8] = {};
        const char* Kb = shb + cur * 32768;
        #pragma unroll
        for (int kvf = 0; kvf < 8; ++kvf) {
            int r = kvf * 16 + l15;
            int sw = (r & 7) << 4;
            #pragma unroll
            for (int d = 0; d < 4; ++d) {
                bf16x8 kf = *(const bf16x8*)(Kb + r * 256 + ((d * 64 + lg * 16) ^ sw));
                sc[kvf] = __builtin_amdgcn_mfma_f32_16x16x32_bf16(qf[d], kf, sc[kvf], 0, 0, 0);
            }
        }

        const bool full = (kv0 + KVB <= qw);
        if (!full) {
            #pragma unroll
            for (int k = 0; k < 8; ++k) {
                #pragma unroll
                for (int r = 0; r < 4; ++r) {
                    int qg = qw + lg * 4 + r;
                    if (kv0 + k * 16 + l15 > qg) sc[k][r] = -1e30f;
                }
            }
        }
        float mx = fmaxf(fmaxf(sc[0][0], sc[0][1]), fmaxf(sc[0][2], sc[0][3]));
        #pragma unroll
        for (int k = 1; k < 8; ++k) {
            float m2 = fmaxf(fmaxf(sc[k][0], sc[k][1]), fmaxf(sc[k][2], sc[k][3]));
            mx = fmaxf(mx, m2);
        }
        mx *= scale;
        #pragma unroll
        for (int off = 8; off >= 1; off >>= 1) mx = fmaxf(mx, __shfl_xor(mx, off, 64));
        if (!__all(mx <= mgrp + 8.0f)) {
            float mn = fmaxf(mgrp, mx);
            float corr = __expf(mgrp - mn);
            #pragma unroll
            for (int r = 0; r < 4; ++r) lsum[r] *= corr;
            #pragma unroll
            for (int df = 0; df < 8; ++df) o_acc[df] *= corr;
            mgrp = mn;
        }
        const float mn = mgrp;

        float ph[4][4];
        #pragma unroll
        for (int r = 0; r < 4; ++r) {
            int ql = lg * 4 + r;
            float psum = 0.0f;
            #pragma unroll
            for (int k = 0; k < 8; ++k) {
                float p = __expf(fmaf(sc[k][r], scale, -mn));
                psum += p;
                if (k < 4) Psw[ql * 72 + k * 16 + l15] = f2bf(p);
                else       ph[r][k - 4] = p;
            }
            lsum[r] += psum;
        }

        const char* Vb = shb + 65536 + cur * 32768;
        {
            bf16x8 pa0 = *(const bf16x8*)&Psw[l15 * 72 + lg * 8];
            bf16x8 pa1 = *(const bf16x8*)&Psw[l15 * 72 + 32 + lg * 8];
            #pragma unroll
            for (int df = 0; df < 8; ++df) {
                int d = df * 16 + l15;
                int sw = (d & 7) << 4;
                const char* vrow = Vb + d * 256;
                bf16x8 v0 = *(const bf16x8*)(vrow + ((lg * 16) ^ sw));
                bf16x8 v1 = *(const bf16x8*)(vrow + ((64 + lg * 16) ^ sw));
                o_acc[df] = __builtin_amdgcn_mfma_f32_16x16x32_bf16(pa0, v0, o_acc[df], 0, 0, 0);
                o_acc[df] = __builtin_amdgcn_mfma_f32_16x16x32_bf16(pa1, v1, o_acc[df], 0, 0, 0);
            }
        }
        #pragma unroll
        for (int r = 0; r < 4; ++r) {
            int ql = lg * 4 + r;
            #pragma unroll
            for (int k = 0; k < 4; ++k)
                Psw[ql * 72 + k * 16 + l15] = f2bf(ph[r][k]);
        }
        {
            bf16x8 pa0 = *(const bf16x8*)&Psw[l15 * 72 + lg * 8];
            bf16x8 pa1 = *(const bf16x8*)&Psw[l15 * 72 + 32 + lg * 8];
            #pragma unroll
            for (int df = 0; df < 8; ++df) {
                int d = df * 16 + l15;
                int sw = (d & 7) << 4;
                const char* vrow = Vb + d * 256;
                bf16x8 v0 = *(const bf16x8*)(vrow + ((128 + lg * 16) ^ sw));
                bf16x8 v1 = *(const bf16x8*)(vrow + ((128 + 64 + lg * 16) ^ sw));
                o_acc[df] = __builtin_amdgcn_mfma_f32_16x16x32_bf16(pa0, v0, o_acc[df], 0, 0, 0);
                o_acc[df] = __builtin_amdgcn_mfma_f32_16x16x32_bf16(pa1, v1, o_acc[df], 0, 0, 0);
            }
        }

        if (hn) {
            VMCNT(0);
            BAR();
        }
    }
#undef STAGE

    float inv[4];
    #pragma unroll
    for (int r = 0; r < 4; ++r) {
        float s = lsum[r];
        #pragma unroll
        for (int off = 8; off >= 1; off >>= 1) s += __shfl_xor(s, off, 64);
        inv[r] = 1.0f / s;
    }
    #pragma unroll
    for (int df = 0; df < 8; ++df) {
        #pragma unroll
        for (int r = 0; r < 4; ++r) {
            int q = qw + lg * 4 + r;
            int d = h * HD + df * 16 + l15;
            O[(size_t)q * HID + d] = f2bf(o_acc[df][r] * inv[r]);
        }
    }
}

extern "C" void kernel_launch(void* const* d_in, const int* in_sizes, int n_in,
                              void* d_out, int out_size, void* d_ws, size_t ws_size,
                              hipStream_t stream)
{
    (void)in_sizes; (void)n_in; (void)out_size;
    const float* X    = (const float*)d_in[0];
    const int*   pos  = (const int*)d_in[1];
    const float* Wq   = (const float*)d_in[2];
    const float* Wk   = (const float*)d_in[3];
    const float* Wv   = (const float*)d_in[4];
    const float* Wo   = (const float*)d_in[5];
    const float* qn_w = (const float*)d_in[6];
    const float* qn_b = (const float*)d_in[7];
    const float* kn_w = (const float*)d_in[8];
    const float* kn_b = (const float*)d_in[9];
    float* out = (float*)d_out;

    unsigned short* Xb    = (unsigned short*)d_ws;
    unsigned short* QKVb  = (unsigned short*)((char*)d_ws + 16777216);
    unsigned short* Wt    = (unsigned short*)((char*)d_ws + 67108864);
    unsigned short* Vtg   = (unsigned short*)((char*)d_ws + 134217728);
    unsigned short* P1    = (unsigned short*)((char*)d_ws + 167772160);
    unsigned short* Ab    = Xb;

    const bool splitQKV = ws_size >= (size_t)218103808;

    (void)hipFuncSetAttribute((const void*)gemm_qkv, hipFuncAttributeMaxDynamicSharedMemorySize, 65536);
    (void)hipFuncSetAttribute((const void*)gemm_wo, hipFuncAttributeMaxDynamicSharedMemorySize, 98304);
    (void)hipFuncSetAttribute((const void*)attn_fwd, hipFuncAttributeMaxDynamicSharedMemorySize, ATTN_LDS);

    dim3 blk(256);

    cvt_f32_bf16<<<dim3((S_LEN * HID / 8 + 255) / 256), blk, 0, stream>>>(X, Xb, S_LEN * HID / 8);

    W3 w3{Wq, Wk, Wv};
    cvt_w_t3<<<dim3(HID / 64, HID / 64, 3), blk, 0, stream>>>(w3, Wt, HID, HID);

    if (splitQKV) {
        gemm_qkv<<<dim3(384, 1, 2), dim3(1024), 65536, stream>>>(
            Xb, Wt, QKVb, QKV_N, HID / 2, HID, (size_t)75497472);
        v_transpose<true><<<dim3(S_LEN / 64, HID / 64), blk, 0, stream>>>(QKVb, P1, Vtg);
        ln_rope<true><<<dim3(S_LEN * 64 / 4), blk, 0, stream>>>(QKVb, P1, qn_w, qn_b, kn_w, kn_b, pos);
    } else {
        gemm_qkv<<<dim3(384, 1, 1), dim3(1024), 65536, stream>>>(
            Xb, Wt, QKVb, QKV_N, HID, HID, (size_t)0);
        v_transpose<false><<<dim3(S_LEN / 64, HID / 64), blk, 0, stream>>>(QKVb, QKVb, Vtg);
        ln_rope<false><<<dim3(S_LEN * 64 / 4), blk, 0, stream>>>(QKVb, QKVb, qn_w, qn_b, kn_w, kn_b, pos);
    }

    attn_fwd<<<dim3(S_LEN / 128, NH), dim3(512), ATTN_LDS, stream>>>(QKVb, Vtg, Ab);

    W3 wo3{Wo, Wo, Wo};
    cvt_w_t3<<<dim3(HID / 64, HID / 64, 1), blk, 0, stream>>>(wo3, Wt, HID, HID);

    gemm_wo<<<dim3(256), dim3(512), 98304, stream>>>(Ab, Wt, out, HID, HID);
}

// Round 20
// 473.826 us; speedup vs baseline: 1.0556x; 1.0556x over previous
//
#include <hip/hip_runtime.h>

#define S_LEN 2048
#define HID 4096
#define NH 32
#define HD 128
#define QKV_N 12288   // 3*HID

typedef __attribute__((ext_vector_type(8))) short bf16x8;
typedef __attribute__((ext_vector_type(4))) float f32x4;

__device__ __forceinline__ unsigned short f2bf(float f) {
    unsigned int u = __float_as_uint(f);
    u += 0x7FFF + ((u >> 16) & 1);
    return (unsigned short)(u >> 16);
}
__device__ __forceinline__ float bf2f(unsigned short h) {
    return __uint_as_float(((unsigned int)h) << 16);
}

typedef __attribute__((address_space(1))) const void gconst_void;
typedef __attribute__((address_space(3))) void lds_void;
__device__ __forceinline__ void gl16(const void* g, void* l) {
    __builtin_amdgcn_global_load_lds((gconst_void*)g, (lds_void*)l, 16, 0, 0);
}

#define VMCNT(n) asm volatile("s_waitcnt vmcnt(" #n ")" ::: "memory")
#define BAR()    do { asm volatile("" ::: "memory"); __builtin_amdgcn_s_barrier(); asm volatile("" ::: "memory"); } while (0)

// ---------------- fp32 -> bf16 linear convert ----------------
__global__ __launch_bounds__(256)
void cvt_f32_bf16(const float* __restrict__ in, unsigned short* __restrict__ out, int n8)
{
    int i = blockIdx.x * 256 + threadIdx.x;
    if (i >= n8) return;
    const float4* p = (const float4*)in + (size_t)i * 2;
    float4 a = p[0], b = p[1];
    bf16x8 o;
    o[0] = (short)f2bf(a.x); o[1] = (short)f2bf(a.y); o[2] = (short)f2bf(a.z); o[3] = (short)f2bf(a.w);
    o[4] = (short)f2bf(b.x); o[5] = (short)f2bf(b.y); o[6] = (short)f2bf(b.z); o[7] = (short)f2bf(b.w);
    *((bf16x8*)out + i) = o;
}

// ---------------- fp32 [K][N] -> bf16 [N][K] transpose-convert (up to 3 weights) ----------------
struct W3 { const float* w0; const float* w1; const float* w2; };

__global__ __launch_bounds__(256)
void cvt_w_t3(W3 ws3, unsigned short* __restrict__ Wt, int N, int K)
{
    __shared__ unsigned short t[64][72];
    const float* W = blockIdx.z == 0 ? ws3.w0 : (blockIdx.z == 1 ? ws3.w1 : ws3.w2);
    unsigned short* Wto = Wt + (size_t)blockIdx.z * N * K;
    const int tid = threadIdx.x;
    const int n0 = blockIdx.x * 64, k0 = blockIdx.y * 64;
    const int c4 = (tid & 15) * 4;
    const int r  = tid >> 4;
    #pragma unroll
    for (int p = 0; p < 4; ++p) {
        float4 v = *(const float4*)&W[(size_t)(k0 + r + p * 16) * N + n0 + c4];
        ushort4 o;
        o.x = f2bf(v.x); o.y = f2bf(v.y); o.z = f2bf(v.z); o.w = f2bf(v.w);
        *(ushort4*)&t[r + p * 16][c4] = o;
    }
    __syncthreads();
    const int n = tid >> 2;
    const int kq = (tid & 3) * 16;
    unsigned short* dst = &Wto[(size_t)(n0 + n) * K + k0 + kq];
    bf16x8 v0, v1;
    #pragma unroll
    for (int j = 0; j < 8; ++j) v0[j] = (short)t[kq + j][n];
    #pragma unroll
    for (int j = 0; j < 8; ++j) v1[j] = (short)t[kq + 8 + j][n];
    *(bf16x8*)dst = v0;
    *(bf16x8*)(dst + 8) = v1;
}

// ---------------- bf16 V slab [s][c] -> Vtg [c][s] transpose (+ optional split-K combine) ----------------
template<bool SPLIT>
__global__ __launch_bounds__(256)
void v_transpose(const unsigned short* __restrict__ P0, const unsigned short* __restrict__ P1,
                 unsigned short* __restrict__ Vtg)
{
    __shared__ unsigned short t[64][72];
    const int tid = threadIdx.x;
    const int s0 = blockIdx.x * 64;
    const int c0 = blockIdx.y * 64;
    #pragma unroll
    for (int i = 0; i < 2; ++i) {
        int idx = i * 256 + tid;
        int r = idx >> 3, c8 = (idx & 7) * 8;
        size_t off = (size_t)(s0 + r) * QKV_N + 2 * HID + c0 + c8;
        bf16x8 a = *(const bf16x8*)&P0[off];
        if (SPLIT) {
            bf16x8 b = *(const bf16x8*)&P1[off];
            #pragma unroll
            for (int j = 0; j < 8; ++j)
                a[j] = (short)f2bf(bf2f((unsigned short)a[j]) + bf2f((unsigned short)b[j]));
        }
        *(bf16x8*)&t[r][c8] = a;
    }
    __syncthreads();
    #pragma unroll
    for (int i = 0; i < 2; ++i) {
        int idx = i * 256 + tid;
        int oc = idx >> 3, os8 = (idx & 7) * 8;
        bf16x8 v;
        #pragma unroll
        for (int j = 0; j < 8; ++j) v[j] = (short)t[os8 + j][oc];
        *(bf16x8*)&Vtg[(size_t)(c0 + oc) * S_LEN + s0 + os8] = v;
    }
}

// ---------------- 256x256 GEMM, bf16 out, optional K-split via blockIdx.z ----------------
// single-barrier free-run K-tile (r13/r16, verified 45-46% MfmaUtil, 0 conflicts)
__device__ __forceinline__ void lda4(bf16x8 af[4][2], const char* base, int rq, int l15, int lg) {
    const int sw = (l15 & 7) << 4;
    #pragma unroll
    for (int i = 0; i < 4; ++i) {
        const char* rb = base + ((rq * 4 + i) * 16 + l15) * 128;
        af[i][0] = *(const bf16x8*)(rb + ((lg * 16) ^ sw));
        af[i][1] = *(const bf16x8*)(rb + ((64 + lg * 16) ^ sw));
    }
}
__device__ __forceinline__ void ldb2(bf16x8 bf[2][2], const char* base, int cq, int l15, int lg) {
    const int sw = (l15 & 7) << 4;
    #pragma unroll
    for (int j = 0; j < 2; ++j) {
        const char* rb = base + ((cq * 2 + j) * 16 + l15) * 128;
        bf[j][0] = *(const bf16x8*)(rb + ((lg * 16) ^ sw));
        bf[j][1] = *(const bf16x8*)(rb + ((64 + lg * 16) ^ sw));
    }
}
__device__ __forceinline__ void mfma16(f32x4 acc[8][4], const bf16x8 af[4][2], const bf16x8 bf[2][2],
                                       int mi0, int nj0) {
    __builtin_amdgcn_s_setprio(1);
    #pragma unroll
    for (int kk = 0; kk < 2; ++kk)
        #pragma unroll
        for (int i = 0; i < 4; ++i)
            #pragma unroll
            for (int j = 0; j < 2; ++j)
                acc[mi0 + i][nj0 + j] =
                    __builtin_amdgcn_mfma_f32_16x16x32_bf16(af[i][kk], bf[j][kk], acc[mi0 + i][nj0 + j], 0, 0, 0);
    __builtin_amdgcn_s_setprio(0);
}
__device__ __forceinline__ void stage2(const unsigned short* g, char* dst, int ldk, int r32, int kn) {
    gl16(g + (size_t)r32 * ldk + kn, dst);
    gl16(g + (size_t)(r32 + 8) * ldk + kn, dst + 1024);
}

__global__ __launch_bounds__(512, 2)
void gemm256(const unsigned short* __restrict__ A,   // [M][ldk] bf16
             const unsigned short* __restrict__ Bt,  // [N][ldk] bf16
             unsigned short* __restrict__ Cp,        // bf16, + z*zstride
             int N, int K, int ldk, size_t zstride)
{
    extern __shared__ char lds[];
    const int tid = threadIdx.x;
    const int l   = tid & 63;
    const int l15 = l & 15, lg = l >> 4;
    const int wid = tid >> 6;
    const int wr  = wid >> 2;
    const int wc  = wid & 3;

    const int nwg = gridDim.x;
    const int bid = blockIdx.x;
    const int ntx = N >> 8;
    const int nty = nwg / ntx;
    const int cpx = ntx >> 3;
    const int xcd = bid & 7;
    const int idx = bid >> 3;
    const int bx = xcd * cpx + idx / nty;
    const int by = idx % nty;
    const int m0 = by * 256, n0 = bx * 256;
    const int koff = blockIdx.z * K;

    char* const Abase = lds + wr * 16384;
    char* const Bbase = lds + 32768 + (wc >> 1) * 16384 + (wc & 1) * 8192;

    const int l8 = l >> 3, l7 = l & 7;
    const int swslot = (l7 ^ l8) << 3;

    const unsigned short* Ag = A  + (size_t)(m0 + wr * 128 + wc * 16 + l8) * ldk + koff + swslot;
    const unsigned short* Bg = Bt + (size_t)(n0 + wc * 64 + wr * 16 + l8) * ldk + koff + swslot;
    char* const Adst = Abase + (wc * 16) * 128 + l * 16;
    char* const Bdst = Bbase + (wr * 16) * 128 + l * 16;

    f32x4 acc[8][4] = {};
    bf16x8 af[4][2], bfA[2][2], bfB[2][2];

    stage2(Ag, Adst, ldk, 0, 0);
    stage2(Bg, Bdst, ldk, 0, 0);
    stage2(Ag, Adst + 64 * 128, ldk, 64, 0);
    stage2(Bg, Bdst + 32 * 128, ldk, 32, 0);
    VMCNT(0);
    BAR();

    const int NT = K >> 6;
    for (int t = 0; t < NT; ++t) {
        const int cb = (t & 1) * 65536, nb = cb ^ 65536;
        const int kn = (t + 1) << 6;
        const bool hn = (t + 1) < NT;

        lda4(af, Abase + cb, 0, l15, lg);
        ldb2(bfA, Bbase + cb, 0, l15, lg);
        if (hn) {
            stage2(Ag, Adst + nb, ldk, 0, kn);
            stage2(Bg, Bdst + nb, ldk, 0, kn);
            stage2(Ag, Adst + nb + 64 * 128, ldk, 64, kn);
            stage2(Bg, Bdst + nb + 32 * 128, ldk, 32, kn);
        }
        mfma16(acc, af, bfA, 0, 0);

        ldb2(bfB, Bbase + cb, 1, l15, lg);
        mfma16(acc, af, bfB, 0, 2);

        lda4(af, Abase + cb, 1, l15, lg);
        mfma16(acc, af, bfB, 4, 2);
        mfma16(acc, af, bfA, 4, 0);

        VMCNT(0);
        BAR();
    }

    unsigned short* C = Cp + (size_t)blockIdx.z * zstride;
    const int crow = m0 + wr * 128 + lg * 4;
    const int ccol = n0 + wc * 64 + l15;
    #pragma unroll
    for (int mi = 0; mi < 8; ++mi)
        #pragma unroll
        for (int nj = 0; nj < 4; ++nj)
            #pragma unroll
            for (int rr = 0; rr < 4; ++rr)
                C[(size_t)(crow + mi * 16 + rr) * N + ccol + nj * 16] = f2bf(acc[mi][nj][rr]);
}

// ---------------- 128x256 GEMM -> fp32 out (Wo projection; 256 blocks = full round, r18-verified) ----------------
__global__ __launch_bounds__(512, 2)
void gemm_wo(const unsigned short* __restrict__ A,   // [M][K] bf16 (M=2048)
             const unsigned short* __restrict__ Bt,  // [N][K] bf16 (N=4096)
             float* __restrict__ out, int N, int K)
{
    extern __shared__ char lds[];
    const int tid = threadIdx.x;
    const int l   = tid & 63;
    const int l15 = l & 15, lg = l >> 4;
    const int wid = tid >> 6;
    const int wr  = wid >> 2;
    const int wc  = wid & 3;

    const int bid = blockIdx.x;
    const int ntx = N >> 8;
    const int nty = 256 / ntx;
    const int cpx = ntx >> 3;
    const int xcd = bid & 7;
    const int idx = bid >> 3;
    const int bx = xcd * cpx + idx / nty;
    const int by = idx % nty;
    const int m0 = by * 128, n0 = bx * 256;

    const int r8 = tid >> 3;
    const int swslot = ((tid & 7) ^ (r8 & 7)) << 3;

    const unsigned short* Ag = A  + (size_t)(m0 + r8) * K + swslot;
    const unsigned short* Bg = Bt + (size_t)(n0 + r8) * K + swslot;

    f32x4 acc[4][4] = {};
    bf16x8 af[4][2], bf[4][2];

    #pragma unroll
    for (int i = 0; i < 2; ++i)
        gl16(Ag + (size_t)i * 64 * K, lds + (i * 512 + tid) * 16);
    #pragma unroll
    for (int i = 0; i < 4; ++i)
        gl16(Bg + (size_t)i * 64 * K, lds + 16384 + (i * 512 + tid) * 16);
    VMCNT(0);
    BAR();

    const int NT = K >> 6;
    for (int t = 0; t < NT; ++t) {
        const int cb = (t & 1) * 49152, nb = cb ^ 49152;
        const int kn = (t + 1) << 6;
        const bool hn = (t + 1) < NT;

        const int sw = (l15 & 7) << 4;
        #pragma unroll
        for (int mi = 0; mi < 4; ++mi) {
            const char* rb = lds + cb + (wr * 64 + mi * 16 + l15) * 128;
            af[mi][0] = *(const bf16x8*)(rb + ((lg * 16) ^ sw));
            af[mi][1] = *(const bf16x8*)(rb + ((64 + lg * 16) ^ sw));
        }
        #pragma unroll
        for (int nj = 0; nj < 4; ++nj) {
            const char* rb = lds + cb + 16384 + (wc * 64 + nj * 16 + l15) * 128;
            bf[nj][0] = *(const bf16x8*)(rb + ((lg * 16) ^ sw));
            bf[nj][1] = *(const bf16x8*)(rb + ((64 + lg * 16) ^ sw));
        }
        if (hn) {
            #pragma unroll
            for (int i = 0; i < 2; ++i)
                gl16(Ag + (size_t)i * 64 * K + kn, lds + nb + (i * 512 + tid) * 16);
            #pragma unroll
            for (int i = 0; i < 4; ++i)
                gl16(Bg + (size_t)i * 64 * K + kn, lds + nb + 16384 + (i * 512 + tid) * 16);
        }
        __builtin_amdgcn_s_setprio(1);
        #pragma unroll
        for (int kk = 0; kk < 2; ++kk)
            #pragma unroll
            for (int mi = 0; mi < 4; ++mi)
                #pragma unroll
                for (int nj = 0; nj < 4; ++nj)
                    acc[mi][nj] = __builtin_amdgcn_mfma_f32_16x16x32_bf16(af[mi][kk], bf[nj][kk], acc[mi][nj], 0, 0, 0);
        __builtin_amdgcn_s_setprio(0);

        VMCNT(0);
        BAR();
    }

    const int crow = m0 + wr * 64 + lg * 4;
    const int ccol = n0 + wc * 64 + l15;
    #pragma unroll
    for (int mi = 0; mi < 4; ++mi)
        #pragma unroll
        for (int nj = 0; nj < 4; ++nj)
            #pragma unroll
            for (int rr = 0; rr < 4; ++rr)
                out[(size_t)(crow + mi * 16 + rr) * N + ccol + nj * 16] = acc[mi][nj][rr];
}

// ---------------- per-head LayerNorm + RoPE (+ optional split-K combine), writes into P0 ----------------
template<bool SPLIT>
__global__ __launch_bounds__(256)
void ln_rope(unsigned short* __restrict__ P0, const unsigned short* __restrict__ P1,
             const float* __restrict__ qg, const float* __restrict__ qb,
             const float* __restrict__ kg, const float* __restrict__ kb,
             const int* __restrict__ pos)
{
    const int tid = threadIdx.x;
    const int l = tid & 63;
    const int w = tid >> 6;
    const int rid = blockIdx.x * 4 + w;
    const int s = rid >> 6;
    const int hh = rid & 63;
    const int which = hh >> 5;
    const int h = hh & 31;
    const size_t off = (size_t)s * QKV_N + which * HID + h * HD;
    unsigned short* p = P0 + off;
    const float* gamma = which ? kg : qg;
    const float* beta  = which ? kb : qb;

    float lo = bf2f(p[l]);
    float hi = bf2f(p[l + 64]);
    if (SPLIT) {
        const unsigned short* q = P1 + off;
        lo += bf2f(q[l]);
        hi += bf2f(q[l + 64]);
    }
    float sum = lo + hi;
    #pragma unroll
    for (int off2 = 32; off2 >= 1; off2 >>= 1) sum += __shfl_xor(sum, off2, 64);
    float mu = sum * (1.0f / 128.0f);
    float dlo = lo - mu, dhi = hi - mu;
    float vs = dlo * dlo + dhi * dhi;
    #pragma unroll
    for (int off2 = 32; off2 >= 1; off2 >>= 1) vs += __shfl_xor(vs, off2, 64);
    float rstd = rsqrtf(vs * (1.0f / 128.0f) + 1e-5f);
    float xlo = dlo * rstd * gamma[l] + beta[l];
    float xhi = dhi * rstd * gamma[l + 64] + beta[l + 64];

    float fpos = (float)pos[s];
    float invf = exp2f(-13.287712379549449f * (float)l * (1.0f / 64.0f));
    float ang = fpos * invf;
    float sn, cs;
    sincosf(ang, &sn, &cs);
    p[l]      = f2bf(xlo * cs - xhi * sn);
    p[l + 64] = f2bf(xhi * cs + xlo * sn);
}

// ---------------- causal flash attention: 8 waves (QBLK=128), KVB=128, 1 barrier/tile ----------------
#define KVB 128
#define ATTN_LDS 149504

__global__ __launch_bounds__(512)
void attn_fwd(const unsigned short* __restrict__ QKV,   // [S][12288]
              const unsigned short* __restrict__ Vtg,   // [4096][S]
              unsigned short* __restrict__ O)           // [S][4096]
{
    extern __shared__ char shb[];
    unsigned short* const Psw = (unsigned short*)(shb + 131072) + (threadIdx.x >> 6) * (16 * 72);

    const int tid = threadIdx.x;
    const int l = tid & 63;
    const int w = tid >> 6;
    const int l15 = l & 15, lg = l >> 4;
    const int h = blockIdx.y;
    const int qb = gridDim.x - 1 - blockIdx.x;
    const int q0 = qb * 128;
    const int qw = q0 + w * 16;

    const unsigned short* Qp = QKV + h * HD;
    const unsigned short* Kp = QKV + HID + h * HD;
    const unsigned short* Vp = Vtg + (size_t)h * HD * S_LEN;

    bf16x8 qf[4];
    #pragma unroll
    for (int d = 0; d < 4; ++d)
        qf[d] = *(const bf16x8*)&Qp[(size_t)(qw + l15) * QKV_N + d * 32 + lg * 8];

    f32x4 o_acc[8] = {};
    float mgrp = -1e30f;
    float lsum[4] = {0.0f, 0.0f, 0.0f, 0.0f};

    const float scale = 0.08838834764831845f;

    const int ksl = tid & 15;
    const int kr7 = (tid >> 4) & 7;
    const int ksg = (ksl & 8) | ((ksl ^ kr7) & 7);
    const unsigned short* Kg = Kp + (size_t)(tid >> 4) * QKV_N + ksg * 8;
    const unsigned short* Vg = Vp + (size_t)(tid >> 4) * S_LEN + ksg * 8;

#define STAGE(buf, kv0s) do {                                                          \
    _Pragma("unroll")                                                                  \
    for (int i_ = 0; i_ < 4; ++i_)                                                     \
        gl16(Kg + (size_t)((kv0s) + i_ * 32) * QKV_N,                                  \
             shb + (buf) * 32768 + (i_ * 512 + tid) * 16);                             \
    _Pragma("unroll")                                                                  \
    for (int i_ = 0; i_ < 4; ++i_)                                                     \
        gl16(Vg + (size_t)i_ * 32 * S_LEN + (kv0s),                                    \
             shb + 65536 + (buf) * 32768 + (i_ * 512 + tid) * 16);                     \
} while (0)

    STAGE(0, 0);
    VMCNT(0);
    __syncthreads();

    const int nt = qb + 1;
    for (int t = 0; t < nt; ++t) {
        const int kv0 = t * KVB;
        const int cur = t & 1;
        const bool hn = (t + 1) < nt;
        if (hn) STAGE(cur ^ 1, kv0 + KVB);

        f32x4 sc[8] = {};
        const char* Kb = shb + cur * 32768;
        #pragma unroll
        for (int kvf = 0; kvf < 8; ++kvf) {
            int r = kvf * 16 + l15;
            int sw = (r & 7) << 4;
            #pragma unroll
            for (int d = 0; d < 4; ++d) {
                bf16x8 kf = *(const bf16x8*)(Kb + r * 256 + ((d * 64 + lg * 16) ^ sw));
                sc[kvf] = __builtin_amdgcn_mfma_f32_16x16x32_bf16(qf[d], kf, sc[kvf], 0, 0, 0);
            }
        }

        const bool full = (kv0 + KVB <= qw);
        if (!full) {
            #pragma unroll
            for (int k = 0; k < 8; ++k) {
                #pragma unroll
                for (int r = 0; r < 4; ++r) {
                    int qg = qw + lg * 4 + r;
                    if (kv0 + k * 16 + l15 > qg) sc[k][r] = -1e30f;
                }
            }
        }
        float mx = fmaxf(fmaxf(sc[0][0], sc[0][1]), fmaxf(sc[0][2], sc[0][3]));
        #pragma unroll
        for (int k = 1; k < 8; ++k) {
            float m2 = fmaxf(fmaxf(sc[k][0], sc[k][1]), fmaxf(sc[k][2], sc[k][3]));
            mx = fmaxf(mx, m2);
        }
        mx *= scale;
        #pragma unroll
        for (int off = 8; off >= 1; off >>= 1) mx = fmaxf(mx, __shfl_xor(mx, off, 64));
        if (!__all(mx <= mgrp + 8.0f)) {
            float mn = fmaxf(mgrp, mx);
            float corr = __expf(mgrp - mn);
            #pragma unroll
            for (int r = 0; r < 4; ++r) lsum[r] *= corr;
            #pragma unroll
            for (int df = 0; df < 8; ++df) o_acc[df] *= corr;
            mgrp = mn;
        }
        const float mn = mgrp;

        float ph[4][4];
        #pragma unroll
        for (int r = 0; r < 4; ++r) {
            int ql = lg * 4 + r;
            float psum = 0.0f;
            #pragma unroll
            for (int k = 0; k < 8; ++k) {
                float p = __expf(fmaf(sc[k][r], scale, -mn));
                psum += p;
                if (k < 4) Psw[ql * 72 + k * 16 + l15] = f2bf(p);
                else       ph[r][k - 4] = p;
            }
            lsum[r] += psum;
        }

        const char* Vb = shb + 65536 + cur * 32768;
        {
            bf16x8 pa0 = *(const bf16x8*)&Psw[l15 * 72 + lg * 8];
            bf16x8 pa1 = *(const bf16x8*)&Psw[l15 * 72 + 32 + lg * 8];
            #pragma unroll
            for (int df = 0; df < 8; ++df) {
                int d = df * 16 + l15;
                int sw = (d & 7) << 4;
                const char* vrow = Vb + d * 256;
                bf16x8 v0 = *(const bf16x8*)(vrow + ((lg * 16) ^ sw));
                bf16x8 v1 = *(const bf16x8*)(vrow + ((64 + lg * 16) ^ sw));
                o_acc[df] = __builtin_amdgcn_mfma_f32_16x16x32_bf16(pa0, v0, o_acc[df], 0, 0, 0);
                o_acc[df] = __builtin_amdgcn_mfma_f32_16x16x32_bf16(pa1, v1, o_acc[df], 0, 0, 0);
            }
        }
        #pragma unroll
        for (int r = 0; r < 4; ++r) {
            int ql = lg * 4 + r;
            #pragma unroll
            for (int k = 0; k < 4; ++k)
                Psw[ql * 72 + k * 16 + l15] = f2bf(ph[r][k]);
        }
        {
            bf16x8 pa0 = *(const bf16x8*)&Psw[l15 * 72 + lg * 8];
            bf16x8 pa1 = *(const bf16x8*)&Psw[l15 * 72 + 32 + lg * 8];
            #pragma unroll
            for (int df = 0; df < 8; ++df) {
                int d = df * 16 + l15;
                int sw = (d & 7) << 4;
                const char* vrow = Vb + d * 256;
                bf16x8 v0 = *(const bf16x8*)(vrow + ((128 + lg * 16) ^ sw));
                bf16x8 v1 = *(const bf16x8*)(vrow + ((128 + 64 + lg * 16) ^ sw));
                o_acc[df] = __builtin_amdgcn_mfma_f32_16x16x32_bf16(pa0, v0, o_acc[df], 0, 0, 0);
                o_acc[df] = __builtin_amdgcn_mfma_f32_16x16x32_bf16(pa1, v1, o_acc[df], 0, 0, 0);
            }
        }

        if (hn) {
            VMCNT(0);
            BAR();
        }
    }
#undef STAGE

    float inv[4];
    #pragma unroll
    for (int r = 0; r < 4; ++r) {
        float s = lsum[r];
        #pragma unroll
        for (int off = 8; off >= 1; off >>= 1) s += __shfl_xor(s, off, 64);
        inv[r] = 1.0f / s;
    }
    #pragma unroll
    for (int df = 0; df < 8; ++df) {
        #pragma unroll
        for (int r = 0; r < 4; ++r) {
            int q = qw + lg * 4 + r;
            int d = h * HD + df * 16 + l15;
            O[(size_t)q * HID + d] = f2bf(o_acc[df][r] * inv[r]);
        }
    }
}

extern "C" void kernel_launch(void* const* d_in, const int* in_sizes, int n_in,
                              void* d_out, int out_size, void* d_ws, size_t ws_size,
                              hipStream_t stream)
{
    (void)in_sizes; (void)n_in; (void)out_size;
    const float* X    = (const float*)d_in[0];
    const int*   pos  = (const int*)d_in[1];
    const float* Wq   = (const float*)d_in[2];
    const float* Wk   = (const float*)d_in[3];
    const float* Wv   = (const float*)d_in[4];
    const float* Wo   = (const float*)d_in[5];
    const float* qn_w = (const float*)d_in[6];
    const float* qn_b = (const float*)d_in[7];
    const float* kn_w = (const float*)d_in[8];
    const float* kn_b = (const float*)d_in[9];
    float* out = (float*)d_out;

    unsigned short* Xb    = (unsigned short*)d_ws;
    unsigned short* QKVb  = (unsigned short*)((char*)d_ws + 16777216);
    unsigned short* Wt    = (unsigned short*)((char*)d_ws + 67108864);
    unsigned short* Vtg   = (unsigned short*)((char*)d_ws + 134217728);
    unsigned short* P1    = (unsigned short*)((char*)d_ws + 167772160);
    unsigned short* Ab    = Xb;

    const bool splitQKV = ws_size >= (size_t)218103808;

    (void)hipFuncSetAttribute((const void*)gemm256, hipFuncAttributeMaxDynamicSharedMemorySize, 131072);
    (void)hipFuncSetAttribute((const void*)gemm_wo, hipFuncAttributeMaxDynamicSharedMemorySize, 98304);
    (void)hipFuncSetAttribute((const void*)attn_fwd, hipFuncAttributeMaxDynamicSharedMemorySize, ATTN_LDS);

    dim3 blk(256);

    cvt_f32_bf16<<<dim3((S_LEN * HID / 8 + 255) / 256), blk, 0, stream>>>(X, Xb, S_LEN * HID / 8);

    W3 w3{Wq, Wk, Wv};
    cvt_w_t3<<<dim3(HID / 64, HID / 64, 3), blk, 0, stream>>>(w3, Wt, HID, HID);

    if (splitQKV) {
        gemm256<<<dim3(384, 1, 2), dim3(512), 131072, stream>>>(
            Xb, Wt, QKVb, QKV_N, HID / 2, HID, (size_t)75497472);
        v_transpose<true><<<dim3(S_LEN / 64, HID / 64), blk, 0, stream>>>(QKVb, P1, Vtg);
        ln_rope<true><<<dim3(S_LEN * 64 / 4), blk, 0, stream>>>(QKVb, P1, qn_w, qn_b, kn_w, kn_b, pos);
    } else {
        gemm256<<<dim3(384, 1, 1), dim3(512), 131072, stream>>>(
            Xb, Wt, QKVb, QKV_N, HID, HID, (size_t)0);
        v_transpose<false><<<dim3(S_LEN / 64, HID / 64), blk, 0, stream>>>(QKVb, QKVb, Vtg);
        ln_rope<false><<<dim3(S_LEN * 64 / 4), blk, 0, stream>>>(QKVb, QKVb, qn_w, qn_b, kn_w, kn_b, pos);
    }

    attn_fwd<<<dim3(S_LEN / 128, NH), dim3(512), ATTN_LDS, stream>>>(QKVb, Vtg, Ab);

    W3 wo3{Wo, Wo, Wo};
    cvt_w_t3<<<dim3(HID / 64, HID / 64, 1), blk, 0, stream>>>(wo3, Wt, HID, HID);

    gemm_wo<<<dim3(256), dim3(512), 98304, stream>>>(Ab, Wt, out, HID, HID);
}